// Round 7
// baseline (273.113 us; speedup 1.0000x reference)
//
#include <hip/hip_runtime.h>

// Residual GCN, MI355X. B=8, N=2048, D=128 fixed. External dtype fp32.
// out = dinv_i * (A @ (dinv_j * leakyrelu(X@W + b))) [+ X]
// Internal pipeline bf16 + MFMA 16x16x32 bf16, fp32 accumulate.
//
// R15: k_gah step-schedule restructure (T3 mechanism), geometry = R14.
//  R10/R12/R13/R14 all land each k_gah at ~55-65us vs ~13us LDS-bound
//  model; the shared structure is the per-step serial region: vmcnt-wait ->
//  barrier -> LDS burst -> barrier -> stage-issue, with 2-step prefetch.
//  Changes (k_gah only):
//   - FOUR 24KB LDS buffers (96KB ring, mod 4) -> prefetch depth 3 steps
//     (~3 step-times of cover >> HBM ~900cyc) so vmcnt(6) at step top is
//     ~free in steady state;
//   - stage issue folded INTO the compute phases (A-stage inside phase s=0,
//     B-stages inside phase s=1) instead of a separate post-barrier region;
//   - s_setprio(1) around each MFMA cluster (wave role diversity exists
//     now: stage-issuing vs MFMA waves);
//   - still 2 barriers/step: top (cross-wave stage visibility: wave X reads
//     rows staged by wave Y), end (WAR: buf re-staged next step; ring
//     distance 4 makes in-step writes hazard-free vs current reads).
//  k_pre / k_gxw unchanged (isolate the variable).
// Numerics identical to R4..R14 (same fragment values, same MFMA order).

typedef short bf16x8 __attribute__((ext_vector_type(8)));
typedef float f32x4 __attribute__((ext_vector_type(4)));

static __device__ __forceinline__ float bf2f(unsigned short h) {
    union { unsigned int u; float f; } v; v.u = ((unsigned int)h) << 16; return v.f;
}
static __device__ __forceinline__ unsigned short f2bf(float x) {  // RNE
    union { float f; unsigned int u; } v; v.f = x;
    return (unsigned short)((v.u + 0x7FFFu + ((v.u >> 16) & 1u)) >> 16);
}

static __device__ __forceinline__ void gl2lds16(const unsigned short* g,
                                                unsigned short* l) {
    __builtin_amdgcn_global_load_lds(
        (const __attribute__((address_space(1))) unsigned int*)g,
        (__attribute__((address_space(3))) unsigned int*)l, 16, 0, 0);
}

// ---- fused: adj rowsum -> dinv, adj fp32 -> bf16, W transpose, bias ------
__global__ __launch_bounds__(256) void k_pre(const float* __restrict__ adj,
                                             const float* __restrict__ W1,
                                             const float* __restrict__ W2,
                                             const float* __restrict__ W3,
                                             const float* __restrict__ b1,
                                             const float* __restrict__ b2,
                                             const float* __restrict__ b3,
                                             float* __restrict__ dinv,
                                             unsigned short* __restrict__ adjb,
                                             unsigned short* __restrict__ WT,
                                             float* __restrict__ biasf) {
    if (blockIdx.x >= 16384) {                        // prep tail: W^T + bias
        const int e = (blockIdx.x - 16384) * 256 + threadIdx.x;
        if (e < 49152) {
            const int w = e >> 14, r = e & 16383;
            const int f = r & 127, k = r >> 7;
            const float* W = (w == 0) ? W1 : ((w == 1) ? W2 : W3);
            WT[w * 16384 + f * 128 + k] = f2bf(W[r]);
        } else if (e < 49536) {
            const int idx = e - 49152;
            const float* bp = (idx < 128) ? b1 : ((idx < 256) ? b2 : b3);
            biasf[idx] = bp[idx & 127];
        }
        return;
    }
    const int row = blockIdx.x;                       // 0..16383
    const size_t base = (size_t)row * 2048 + threadIdx.x * 8;
    const float4 a = *(const float4*)(adj + base);
    const float4 b = *(const float4*)(adj + base + 4);
    float s = a.x + a.y + a.z + a.w + b.x + b.y + b.z + b.w;
    union { uint4 u; unsigned short h[8]; } pk;
    pk.h[0] = f2bf(a.x); pk.h[1] = f2bf(a.y); pk.h[2] = f2bf(a.z); pk.h[3] = f2bf(a.w);
    pk.h[4] = f2bf(b.x); pk.h[5] = f2bf(b.y); pk.h[6] = f2bf(b.z); pk.h[7] = f2bf(b.w);
    *(uint4*)(adjb + base) = pk.u;
#pragma unroll
    for (int off = 32; off > 0; off >>= 1) s += __shfl_down(s, off);
    __shared__ float ws[4];
    if ((threadIdx.x & 63) == 0) ws[threadIdx.x >> 6] = s;
    __syncthreads();
    if (threadIdx.x == 0) {
        float t = ws[0] + ws[1] + ws[2] + ws[3];
        dinv[row] = (t > 0.f) ? rsqrtf(t) : 0.f;      // matches where(isinf,0)
    }
}

// ---- small GEMM: Hs = leakyrelu(X @ W + b) * dinv_j -> HsT (transposed) --
// Stage full 128x128 WT in LDS once (one barrier), then barrier-free MFMA.
// 512 blocks x 4 waves; block = 32 rows; wave = 16 rows x 64 f.
template <int AEXT>
__global__ __launch_bounds__(256) void k_gxw(const void* __restrict__ Asrc,
                                             const unsigned short* __restrict__ WTb,
                                             const float* __restrict__ biasf,
                                             const float* __restrict__ dinv,
                                             unsigned short* __restrict__ HsT) {
    constexpr int LDK = 136;                          // 128 + 8 pad
    __shared__ unsigned short Bs[128 * LDK];          // 34 KB

    const int tid  = threadIdx.x;
    const int wave = tid >> 6;
    const int lane = tid & 63;
    const int n_   = lane & 15;
    const int q    = lane >> 4;
    const int wm   = wave >> 1;                       // row half 0..1
    const int ch   = wave & 1;                        // col half 0..1

    const int r0 = blockIdx.x * 32;                   // 512 blocks

#pragma unroll
    for (int it = 0; it < 8; ++it) {                  // stage full 128x128 WT
        int task = tid + it * 256;
        int f  = task >> 4;
        int cj = (task & 15) * 8;
        *(uint4*)(&Bs[f * LDK + cj]) = *(const uint4*)(WTb + f * 128 + cj);
    }
    __syncthreads();

    const int arow = r0 + wm * 16 + n_;
    bf16x8 av[4];
#pragma unroll
    for (int s = 0; s < 4; ++s) {
        if (AEXT) {
            const float* p = (const float*)Asrc + (size_t)arow * 128 + s * 32 + q * 8;
            float4 uu = ((const float4*)p)[0], w = ((const float4*)p)[1];
            union { bf16x8 v; unsigned short h[8]; } r;
            r.h[0] = f2bf(uu.x); r.h[1] = f2bf(uu.y); r.h[2] = f2bf(uu.z); r.h[3] = f2bf(uu.w);
            r.h[4] = f2bf(w.x);  r.h[5] = f2bf(w.y);  r.h[6] = f2bf(w.z);  r.h[7] = f2bf(w.w);
            av[s] = r.v;
        } else {
            av[s] = *(const bf16x8*)((const unsigned short*)Asrc + (size_t)arow * 128 + s * 32 + q * 8);
        }
    }

    f32x4 acc[4];
#pragma unroll
    for (int i = 0; i < 4; ++i) acc[i] = (f32x4){0.f, 0.f, 0.f, 0.f};
#pragma unroll
    for (int s = 0; s < 4; ++s) {
#pragma unroll
        for (int nt = 0; nt < 4; ++nt) {
            bf16x8 bv = *(const bf16x8*)(&Bs[(ch * 64 + nt * 16 + n_) * LDK + s * 32 + q * 8]);
            acc[nt] = __builtin_amdgcn_mfma_f32_16x16x32_bf16(av[s], bv, acc[nt], 0, 0, 0);
        }
    }

    // C/D: col = lane&15, row = quad*4 + reg
    const int rbase = r0 + wm * 16 + q * 4;
    float dsc[4];
#pragma unroll
    for (int r = 0; r < 4; ++r) dsc[r] = dinv[rbase + r];
    const int b  = rbase >> 11;
    const int jb = rbase & 2047;
    unsigned short* Hb = HsT + (size_t)b * (128 * 2048);
#pragma unroll
    for (int nt = 0; nt < 4; ++nt) {
        const int f = ch * 64 + nt * 16 + n_;
        const float bf = biasf[f];
        unsigned short pk[4];
#pragma unroll
        for (int r = 0; r < 4; ++r) {
            float v = acc[nt][r] + bf;
            v = (v > 0.f) ? v : 0.01f * v;            // LeakyReLU(0.01)
            pk[r] = f2bf(v * dsc[r]);                 // * dinv_j
        }
        uint2 uo;
        uo.x = (unsigned int)pk[0] | ((unsigned int)pk[1] << 16);
        uo.y = (unsigned int)pk[2] | ((unsigned int)pk[3] << 16);
        *(uint2*)(Hb + (size_t)f * 2048 + jb) = uo;   // HsT[b][f][j]
    }
}

// ---- big GEMM: out = (adjb @ HsT^T) * dinv_i [+resid] --------------------
// 256 blocks (1/CU), 512 threads (8 waves), block = 64 rows x 128 f,
// K = 2048 in 32 steps of 64. Staging via global_load_lds (pre-swizzled
// source chunk ^= row&7, swizzled ds_read), FOUR 24KB buffers (ring mod 4,
// depth-3), counted vmcnt(6), raw barriers; stage issue folded into the
// two compute phases; setprio around MFMA clusters. No vmcnt(0) in loop.
// Wave (wm = w>>2, wn = w&3): 32 rows x 32 f, acc 2x2 16x16 frags.
// MODE 1: store (*dinv_i); MODE 2: +resid. OUT32: fp32 store else bf16.
template <int MODE, int OUT32>
__global__ __launch_bounds__(512, 1) void k_gah(const unsigned short* __restrict__ adjb,
                                                const unsigned short* __restrict__ HsT,
                                                const float* __restrict__ dinv,
                                                const unsigned short* __restrict__ resid,
                                                void* __restrict__ outp) {
    constexpr int ABUFE = 64 * 64;                    // 4096 elems (8KB)
    constexpr int BBUFE = 128 * 64;                   // 8192 elems (16KB)
    constexpr int BUFE  = ABUFE + BBUFE;              // 12288 elems (24KB)
    __shared__ unsigned short Sm[4 * BUFE];           // 96KB -> 1 block/CU

    const int tid  = threadIdx.x;
    const int wave = tid >> 6;                        // 0..7
    const int lane = tid & 63;
    const int n_   = lane & 15;
    const int q    = lane >> 4;
    const int wm   = wave >> 2;                       // row half 0..1
    const int wn   = wave & 3;                        // f quarter 0..3

    const int bb = blockIdx.x;                        // 256 blocks
    const int b  = bb & 7;                            // batch -> XCD affinity
    const int rt = bb >> 3;                           // 0..31
    const int row0 = b * 2048 + rt * 64;

    const unsigned short* Ag = adjb + (size_t)row0 * 2048;
    const unsigned short* Bg = HsT + (size_t)b * (128 * 2048);

    // --- staging geometry (global_load_lds: lane l -> wavebase + l*16B) ---
    // decode within a 1KB wave-op: row_sub = l>>3, chunk = l&7.
    // pre-swizzled source chunk = (l&7) ^ (l>>3).
    const int lr  = lane >> 3;                        // 0..7
    const int sch = (lane & 7) ^ lr;                  // swizzled src chunk
    // A: wave w stages tile rows w*8 + lr (64 rows total).
    const unsigned short* Asg = Ag + (size_t)(wave * 8 + lr) * 2048 + sch * 8;
    const int dstA = wave * 512;                      // elems, wave-uniform
    // B: wave w stages f-rows w*16 + i*8 + lr, i = 0,1 (128 rows total).
    const unsigned short* Bsg0 = Bg + (size_t)(wave * 16 + lr) * 2048 + sch * 8;
    const unsigned short* Bsg1 = Bsg0 + 8 * 2048;
    const int dstB = ABUFE + wave * 1024;             // elems, wave-uniform

    // --- read geometry (swizzled ds_read) ---------------------------------
    // A row r: off = r*64 + ((s*4+q)^(r&7))*8; row = wm*32 + mi*16 + n_.
    // B f-row fr: off = ABUFE + fr*64 + ...; fr = wn*32 + nj*16 + n_.
    const int swz = n_ & 7;
    int aoff[2][2], boff[2][2];
#pragma unroll
    for (int mi = 0; mi < 2; ++mi)
#pragma unroll
        for (int s = 0; s < 2; ++s)
            aoff[mi][s] = (wm * 32 + mi * 16 + n_) * 64 + (((s * 4 + q) ^ swz) * 8);
#pragma unroll
    for (int nj = 0; nj < 2; ++nj)
#pragma unroll
        for (int s = 0; s < 2; ++s)
            boff[nj][s] = ABUFE + (wn * 32 + nj * 16 + n_) * 64 + (((s * 4 + q) ^ swz) * 8);

    f32x4 acc[2][2];
#pragma unroll
    for (int i = 0; i < 2; ++i)
#pragma unroll
        for (int j = 0; j < 2; ++j) acc[i][j] = (f32x4){0.f, 0.f, 0.f, 0.f};

    // --- prologue: stage tiles 0,1,2 into buffers 0,1,2 (9 ops/wave) ------
#pragma unroll
    for (int t = 0; t < 3; ++t) {
        const int kofs = t * 64;
        unsigned short* base = &Sm[t * BUFE];
        gl2lds16(Asg + kofs, base + dstA);
        gl2lds16(Bsg0 + kofs, base + dstB);
        gl2lds16(Bsg1 + kofs, base + dstB + 512);
    }

#pragma unroll 1
    for (int t = 0; t < 32; ++t) {
        // newer in flight: tiles t+1, t+2 (6 ops) -> tile t landed
        asm volatile("s_waitcnt vmcnt(6)" ::: "memory");
        __builtin_amdgcn_s_barrier();                 // all waves' t-stages visible
        asm volatile("" ::: "memory");
        const unsigned short* sb = &Sm[(t & 3) * BUFE];
        unsigned short* sw = &Sm[((t + 3) & 3) * BUFE];  // != (t&3); read-safe
        const int kofs = ((t + 3) & 31) * 64;         // tail wraps (never read)
        // ---- phase s=0: reads + A-stage + MFMA ----
        {
            bf16x8 a0 = *(const bf16x8*)(sb + aoff[0][0]);
            bf16x8 a1 = *(const bf16x8*)(sb + aoff[1][0]);
            bf16x8 b0 = *(const bf16x8*)(sb + boff[0][0]);
            bf16x8 b1 = *(const bf16x8*)(sb + boff[1][0]);
            gl2lds16(Asg + kofs, sw + dstA);
            __builtin_amdgcn_s_setprio(1);
            acc[0][0] = __builtin_amdgcn_mfma_f32_16x16x32_bf16(a0, b0, acc[0][0], 0, 0, 0);
            acc[1][0] = __builtin_amdgcn_mfma_f32_16x16x32_bf16(a1, b0, acc[1][0], 0, 0, 0);
            acc[0][1] = __builtin_amdgcn_mfma_f32_16x16x32_bf16(a0, b1, acc[0][1], 0, 0, 0);
            acc[1][1] = __builtin_amdgcn_mfma_f32_16x16x32_bf16(a1, b1, acc[1][1], 0, 0, 0);
            __builtin_amdgcn_s_setprio(0);
        }
        // ---- phase s=1: reads + B-stages + MFMA ----
        {
            bf16x8 a0 = *(const bf16x8*)(sb + aoff[0][1]);
            bf16x8 a1 = *(const bf16x8*)(sb + aoff[1][1]);
            bf16x8 b0 = *(const bf16x8*)(sb + boff[0][1]);
            bf16x8 b1 = *(const bf16x8*)(sb + boff[1][1]);
            gl2lds16(Bsg0 + kofs, sw + dstB);
            gl2lds16(Bsg1 + kofs, sw + dstB + 512);
            __builtin_amdgcn_s_setprio(1);
            acc[0][0] = __builtin_amdgcn_mfma_f32_16x16x32_bf16(a0, b0, acc[0][0], 0, 0, 0);
            acc[1][0] = __builtin_amdgcn_mfma_f32_16x16x32_bf16(a1, b0, acc[1][0], 0, 0, 0);
            acc[0][1] = __builtin_amdgcn_mfma_f32_16x16x32_bf16(a0, b1, acc[0][1], 0, 0, 0);
            acc[1][1] = __builtin_amdgcn_mfma_f32_16x16x32_bf16(a1, b1, acc[1][1], 0, 0, 0);
            __builtin_amdgcn_s_setprio(0);
        }
        asm volatile("" ::: "memory");
        __builtin_amdgcn_s_barrier();                 // WAR: buf (t+1)&3 re-staged next
    }

    // epilogue. C/D: col = lane&15, row = quad*4 + reg
    const int rb = row0 + wm * 32 + q * 4;
    float dsc[2][4];
#pragma unroll
    for (int mi = 0; mi < 2; ++mi)
#pragma unroll
        for (int r = 0; r < 4; ++r) dsc[mi][r] = dinv[rb + mi * 16 + r];
#pragma unroll
    for (int mi = 0; mi < 2; ++mi) {
#pragma unroll
        for (int nj = 0; nj < 2; ++nj) {
            const int f = wn * 32 + nj * 16 + n_;
#pragma unroll
            for (int r = 0; r < 4; ++r) {
                const size_t gr = (size_t)(rb + mi * 16 + r);
                float v = acc[mi][nj][r] * dsc[mi][r];    // * dinv_i
                if (MODE == 2) v += bf2f(resid[gr * 128 + f]);
                if (OUT32) ((float*)outp)[gr * 128 + f] = v;
                else ((unsigned short*)outp)[gr * 128 + f] = f2bf(v);
            }
        }
    }
}

extern "C" void kernel_launch(void* const* d_in, const int* in_sizes, int n_in,
                              void* d_out, int out_size, void* d_ws, size_t ws_size,
                              hipStream_t stream) {
    const float* X   = (const float*)d_in[0];
    const float* adj = (const float*)d_in[1];
    const float* W1  = (const float*)d_in[2];
    const float* b1  = (const float*)d_in[3];
    const float* W2  = (const float*)d_in[4];
    const float* b2  = (const float*)d_in[5];
    const float* W3  = (const float*)d_in[6];
    const float* b3  = (const float*)d_in[7];

    // ws: adjb @0 (64 MiB) | dinv @64M (64K) | biasf @64M+64K | WT @64M+128K
    //     (96K) | HsT @64M+256K (4M) | Xa @68M+256K (4M) | X2 @72M+256K (4M)
    char* ws = (char*)d_ws;
    unsigned short* adjb  = (unsigned short*)ws;
    float*          dinv  = (float*)(ws + (64u << 20));
    float*          biasf = (float*)(ws + (64u << 20) + (64u << 10));
    unsigned short* WT    = (unsigned short*)(ws + (64u << 20) + (128u << 10));
    unsigned short* HsT   = (unsigned short*)(ws + (64u << 20) + (256u << 10));
    unsigned short* Xa    = (unsigned short*)(ws + (68u << 20) + (256u << 10));
    unsigned short* X2    = (unsigned short*)(ws + (72u << 20) + (256u << 10));

    k_pre<<<16578, 256, 0, stream>>>(adj, W1, W2, W3, b1, b2, b3, dinv, adjb, WT, biasf);

    // layer 1
    k_gxw<1><<<512, 256, 0, stream>>>(X, WT, biasf, dinv, HsT);
    k_gah<1, 0><<<256, 512, 0, stream>>>(adjb, HsT, dinv, nullptr, Xa);
    // layer 2 (residual = Xa)
    k_gxw<0><<<512, 256, 0, stream>>>(Xa, WT + 16384, biasf + 128, dinv, HsT);
    k_gah<2, 0><<<256, 512, 0, stream>>>(adjb, HsT, dinv, Xa, X2);
    // layer 3 -> fp32 out
    k_gxw<0><<<512, 256, 0, stream>>>(X2, WT + 32768, biasf + 256, dinv, HsT);
    k_gah<1, 1><<<256, 512, 0, stream>>>(adjb, HsT, dinv, nullptr, (float*)d_out);
}

// Round 8
// 262.084 us; speedup vs baseline: 1.0421x; 1.0421x over previous
//
#include <hip/hip_runtime.h>

// Residual GCN, MI355X. B=8, N=2048, D=128 fixed. External dtype fp32.
// out = dinv_i * (A @ (dinv_j * leakyrelu(X@W + b))) [+ X]
// Internal pipeline bf16 + MFMA 16x16x32 bf16, fp32 accumulate.
//
// R16: dispatch fusion. Five structurally distinct gah schedules (R10-R15)
//  all land within +-15% while LDS/MFMA/HBM are each <25% busy in every
//  model -> either gah has an insensitive ~60us cost or per-dispatch
//  overhead is large and gah is ~35us. Fusion helps under BOTH readings:
//  a gah block computes COMPLETE rows (64 x all 128 f) of the layer output,
//  which is exactly the next gxw's input -> run gxw(l+1) in gah(l)'s
//  epilogue: out-tile -> padded LDS, reg-stage W^T (padded, the proven gxw
//  pattern), one barrier, 16 MFMA/wave mini-GEMM, gxw-identical epilogue ->
//  HsT_next. Removes 2 dispatches, 2x17MB of WT re-staging, and the whole
//  X2 round-trip. HsT ping-pong (HsTa/HsTb) kills the read/write race.
//  K-loop + staging copied VERBATIM from R14 (best measured, 271.1us);
//  all accumulation orders preserved -> bit-identical numerics.
//  Dispatches: k_pre, k_gxw1, k_gahx1(->Xa,HsTb), k_gahx2(+resid->HsTa),
//  k_gah3(->out fp32).

typedef short bf16x8 __attribute__((ext_vector_type(8)));
typedef float f32x4 __attribute__((ext_vector_type(4)));

static __device__ __forceinline__ float bf2f(unsigned short h) {
    union { unsigned int u; float f; } v; v.u = ((unsigned int)h) << 16; return v.f;
}
static __device__ __forceinline__ unsigned short f2bf(float x) {  // RNE
    union { float f; unsigned int u; } v; v.f = x;
    return (unsigned short)((v.u + 0x7FFFu + ((v.u >> 16) & 1u)) >> 16);
}

static __device__ __forceinline__ void gl2lds16(const unsigned short* g,
                                                unsigned short* l) {
    __builtin_amdgcn_global_load_lds(
        (const __attribute__((address_space(1))) unsigned int*)g,
        (__attribute__((address_space(3))) unsigned int*)l, 16, 0, 0);
}

// ---- fused: adj rowsum -> dinv, adj fp32 -> bf16, W transpose, bias ------
__global__ __launch_bounds__(256) void k_pre(const float* __restrict__ adj,
                                             const float* __restrict__ W1,
                                             const float* __restrict__ W2,
                                             const float* __restrict__ W3,
                                             const float* __restrict__ b1,
                                             const float* __restrict__ b2,
                                             const float* __restrict__ b3,
                                             float* __restrict__ dinv,
                                             unsigned short* __restrict__ adjb,
                                             unsigned short* __restrict__ WT,
                                             float* __restrict__ biasf) {
    if (blockIdx.x >= 16384) {                        // prep tail: W^T + bias
        const int e = (blockIdx.x - 16384) * 256 + threadIdx.x;
        if (e < 49152) {
            const int w = e >> 14, r = e & 16383;
            const int f = r & 127, k = r >> 7;
            const float* W = (w == 0) ? W1 : ((w == 1) ? W2 : W3);
            WT[w * 16384 + f * 128 + k] = f2bf(W[r]);
        } else if (e < 49536) {
            const int idx = e - 49152;
            const float* bp = (idx < 128) ? b1 : ((idx < 256) ? b2 : b3);
            biasf[idx] = bp[idx & 127];
        }
        return;
    }
    const int row = blockIdx.x;                       // 0..16383
    const size_t base = (size_t)row * 2048 + threadIdx.x * 8;
    const float4 a = *(const float4*)(adj + base);
    const float4 b = *(const float4*)(adj + base + 4);
    float s = a.x + a.y + a.z + a.w + b.x + b.y + b.z + b.w;
    union { uint4 u; unsigned short h[8]; } pk;
    pk.h[0] = f2bf(a.x); pk.h[1] = f2bf(a.y); pk.h[2] = f2bf(a.z); pk.h[3] = f2bf(a.w);
    pk.h[4] = f2bf(b.x); pk.h[5] = f2bf(b.y); pk.h[6] = f2bf(b.z); pk.h[7] = f2bf(b.w);
    *(uint4*)(adjb + base) = pk.u;
#pragma unroll
    for (int off = 32; off > 0; off >>= 1) s += __shfl_down(s, off);
    __shared__ float ws[4];
    if ((threadIdx.x & 63) == 0) ws[threadIdx.x >> 6] = s;
    __syncthreads();
    if (threadIdx.x == 0) {
        float t = ws[0] + ws[1] + ws[2] + ws[3];
        dinv[row] = (t > 0.f) ? rsqrtf(t) : 0.f;      // matches where(isinf,0)
    }
}

// ---- small GEMM: Hs = leakyrelu(X @ W + b) * dinv_j -> HsT (layer 1) -----
template <int AEXT>
__global__ __launch_bounds__(256) void k_gxw(const void* __restrict__ Asrc,
                                             const unsigned short* __restrict__ WTb,
                                             const float* __restrict__ biasf,
                                             const float* __restrict__ dinv,
                                             unsigned short* __restrict__ HsT) {
    constexpr int LDK = 136;                          // 128 + 8 pad
    __shared__ unsigned short Bs[128 * LDK];          // 34 KB

    const int tid  = threadIdx.x;
    const int wave = tid >> 6;
    const int lane = tid & 63;
    const int n_   = lane & 15;
    const int q    = lane >> 4;
    const int wm   = wave >> 1;                       // row half 0..1
    const int ch   = wave & 1;                        // col half 0..1

    const int r0 = blockIdx.x * 32;                   // 512 blocks

#pragma unroll
    for (int it = 0; it < 8; ++it) {                  // stage full 128x128 WT
        int task = tid + it * 256;
        int f  = task >> 4;
        int cj = (task & 15) * 8;
        *(uint4*)(&Bs[f * LDK + cj]) = *(const uint4*)(WTb + f * 128 + cj);
    }
    __syncthreads();

    const int arow = r0 + wm * 16 + n_;
    bf16x8 av[4];
#pragma unroll
    for (int s = 0; s < 4; ++s) {
        if (AEXT) {
            const float* p = (const float*)Asrc + (size_t)arow * 128 + s * 32 + q * 8;
            float4 uu = ((const float4*)p)[0], w = ((const float4*)p)[1];
            union { bf16x8 v; unsigned short h[8]; } r;
            r.h[0] = f2bf(uu.x); r.h[1] = f2bf(uu.y); r.h[2] = f2bf(uu.z); r.h[3] = f2bf(uu.w);
            r.h[4] = f2bf(w.x);  r.h[5] = f2bf(w.y);  r.h[6] = f2bf(w.z);  r.h[7] = f2bf(w.w);
            av[s] = r.v;
        } else {
            av[s] = *(const bf16x8*)((const unsigned short*)Asrc + (size_t)arow * 128 + s * 32 + q * 8);
        }
    }

    f32x4 acc[4];
#pragma unroll
    for (int i = 0; i < 4; ++i) acc[i] = (f32x4){0.f, 0.f, 0.f, 0.f};
#pragma unroll
    for (int s = 0; s < 4; ++s) {
#pragma unroll
        for (int nt = 0; nt < 4; ++nt) {
            bf16x8 bv = *(const bf16x8*)(&Bs[(ch * 64 + nt * 16 + n_) * LDK + s * 32 + q * 8]);
            acc[nt] = __builtin_amdgcn_mfma_f32_16x16x32_bf16(av[s], bv, acc[nt], 0, 0, 0);
        }
    }

    // C/D: col = lane&15, row = quad*4 + reg
    const int rbase = r0 + wm * 16 + q * 4;
    float dsc[4];
#pragma unroll
    for (int r = 0; r < 4; ++r) dsc[r] = dinv[rbase + r];
    const int b  = rbase >> 11;
    const int jb = rbase & 2047;
    unsigned short* Hb = HsT + (size_t)b * (128 * 2048);
#pragma unroll
    for (int nt = 0; nt < 4; ++nt) {
        const int f = ch * 64 + nt * 16 + n_;
        const float bf = biasf[f];
        unsigned short pk[4];
#pragma unroll
        for (int r = 0; r < 4; ++r) {
            float v = acc[nt][r] + bf;
            v = (v > 0.f) ? v : 0.01f * v;            // LeakyReLU(0.01)
            pk[r] = f2bf(v * dsc[r]);                 // * dinv_j
        }
        uint2 uo;
        uo.x = (unsigned int)pk[0] | ((unsigned int)pk[1] << 16);
        uo.y = (unsigned int)pk[2] | ((unsigned int)pk[3] << 16);
        *(uint2*)(Hb + (size_t)f * 2048 + jb) = uo;   // HsT[b][f][j]
    }
}

// ======== shared K-loop macro-geometry for k_gah / k_gahx (R14 verbatim) ==
// 256 blocks, 512 threads (8 waves), block = 64 rows x 128 f, K = 2048 in
// 32 steps of 64. global_load_lds staging (pre-swizzled src chunk ^= row&7,
// swizzled ds_read), 3 x 24KB buffers, counted vmcnt(6), raw barriers.

// ---- plain big GEMM (layer 3): out = (adjb @ HsT^T) * dinv_i -------------
template <int MODE, int OUT32>
__global__ __launch_bounds__(512, 1) void k_gah(const unsigned short* __restrict__ adjb,
                                                const unsigned short* __restrict__ HsT,
                                                const float* __restrict__ dinv,
                                                const unsigned short* __restrict__ resid,
                                                void* __restrict__ outp) {
    constexpr int ABUFE = 64 * 64;
    constexpr int BBUFE = 128 * 64;
    constexpr int BUFE  = ABUFE + BBUFE;              // 12288 elems (24KB)
    __shared__ unsigned short Sm[3 * BUFE];           // 72KB

    const int tid  = threadIdx.x;
    const int wave = tid >> 6;
    const int lane = tid & 63;
    const int n_   = lane & 15;
    const int q    = lane >> 4;
    const int wm   = wave >> 2;
    const int wn   = wave & 3;

    const int bb = blockIdx.x;
    const int b  = bb & 7;
    const int rt = bb >> 3;
    const int row0 = b * 2048 + rt * 64;

    const unsigned short* Ag = adjb + (size_t)row0 * 2048;
    const unsigned short* Bg = HsT + (size_t)b * (128 * 2048);

    const int lr  = lane >> 3;
    const int sch = (lane & 7) ^ lr;
    const unsigned short* Asg = Ag + (size_t)(wave * 8 + lr) * 2048 + sch * 8;
    const int dstA = wave * 512;
    const unsigned short* Bsg0 = Bg + (size_t)(wave * 16 + lr) * 2048 + sch * 8;
    const unsigned short* Bsg1 = Bsg0 + 8 * 2048;
    const int dstB = ABUFE + wave * 1024;

    const int swz = n_ & 7;
    int aoff[2][2], boff[2][2];
#pragma unroll
    for (int mi = 0; mi < 2; ++mi)
#pragma unroll
        for (int s = 0; s < 2; ++s)
            aoff[mi][s] = (wm * 32 + mi * 16 + n_) * 64 + (((s * 4 + q) ^ swz) * 8);
#pragma unroll
    for (int nj = 0; nj < 2; ++nj)
#pragma unroll
        for (int s = 0; s < 2; ++s)
            boff[nj][s] = ABUFE + (wn * 32 + nj * 16 + n_) * 64 + (((s * 4 + q) ^ swz) * 8);

    f32x4 acc[2][2];
#pragma unroll
    for (int i = 0; i < 2; ++i)
#pragma unroll
        for (int j = 0; j < 2; ++j) acc[i][j] = (f32x4){0.f, 0.f, 0.f, 0.f};

#pragma unroll
    for (int t = 0; t < 3; ++t) {
        const int kofs = t * 64;
        unsigned short* base = &Sm[t * BUFE];
        gl2lds16(Asg + kofs, base + dstA);
        gl2lds16(Bsg0 + kofs, base + dstB);
        gl2lds16(Bsg1 + kofs, base + dstB + 512);
    }

    int cur = 0;
#pragma unroll 1
    for (int t = 0; t < 32; ++t) {
        asm volatile("s_waitcnt vmcnt(6)" ::: "memory");
        __builtin_amdgcn_s_barrier();
        asm volatile("" ::: "memory");
        const unsigned short* sb = &Sm[cur * BUFE];
#pragma unroll
        for (int s = 0; s < 2; ++s) {
            bf16x8 a0 = *(const bf16x8*)(sb + aoff[0][s]);
            bf16x8 a1 = *(const bf16x8*)(sb + aoff[1][s]);
            bf16x8 b0 = *(const bf16x8*)(sb + boff[0][s]);
            bf16x8 b1 = *(const bf16x8*)(sb + boff[1][s]);
            acc[0][0] = __builtin_amdgcn_mfma_f32_16x16x32_bf16(a0, b0, acc[0][0], 0, 0, 0);
            acc[1][0] = __builtin_amdgcn_mfma_f32_16x16x32_bf16(a1, b0, acc[1][0], 0, 0, 0);
            acc[0][1] = __builtin_amdgcn_mfma_f32_16x16x32_bf16(a0, b1, acc[0][1], 0, 0, 0);
            acc[1][1] = __builtin_amdgcn_mfma_f32_16x16x32_bf16(a1, b1, acc[1][1], 0, 0, 0);
        }
        asm volatile("" ::: "memory");
        __builtin_amdgcn_s_barrier();
        asm volatile("" ::: "memory");
        {
            const int kofs = ((t + 3) & 31) * 64;
            unsigned short* base = &Sm[cur * BUFE];
            gl2lds16(Asg + kofs, base + dstA);
            gl2lds16(Bsg0 + kofs, base + dstB);
            gl2lds16(Bsg1 + kofs, base + dstB + 512);
        }
        cur = (cur == 2) ? 0 : cur + 1;
    }

    const int rb = row0 + wm * 32 + q * 4;
    float dsc[2][4];
#pragma unroll
    for (int mi = 0; mi < 2; ++mi)
#pragma unroll
        for (int r = 0; r < 4; ++r) dsc[mi][r] = dinv[rb + mi * 16 + r];
#pragma unroll
    for (int mi = 0; mi < 2; ++mi) {
#pragma unroll
        for (int nj = 0; nj < 2; ++nj) {
            const int f = wn * 32 + nj * 16 + n_;
#pragma unroll
            for (int r = 0; r < 4; ++r) {
                const size_t gr = (size_t)(rb + mi * 16 + r);
                float v = acc[mi][nj][r] * dsc[mi][r];
                if (MODE == 2) v += bf2f(resid[gr * 128 + f]);
                if (OUT32) ((float*)outp)[gr * 128 + f] = v;
                else ((unsigned short*)outp)[gr * 128 + f] = f2bf(v);
            }
        }
    }
}

// ---- fused big GEMM + next-layer gxw (layers 1 and 2) --------------------
// Same K-loop as k_gah; epilogue additionally: out-tile -> padded LDS X-tile,
// reg-stage WTn (padded), barrier, 16-MFMA/wave mini-GEMM (gxw k-order),
// gxw-identical epilogue -> HsTout. WRX: also write X rows (bf16) to Xout.
template <int MODE, int WRX>
__global__ __launch_bounds__(512, 1) void k_gahx(const unsigned short* __restrict__ adjb,
                                                 const unsigned short* __restrict__ HsTin,
                                                 const float* __restrict__ dinv,
                                                 const unsigned short* __restrict__ resid,
                                                 unsigned short* __restrict__ Xout,
                                                 const unsigned short* __restrict__ WTn,
                                                 const float* __restrict__ biasn,
                                                 unsigned short* __restrict__ HsTout) {
    constexpr int ABUFE = 64 * 64;
    constexpr int BBUFE = 128 * 64;
    constexpr int BUFE  = ABUFE + BBUFE;              // 12288 elems
    constexpr int LDX   = 136;                        // padded row stride
    constexpr int XW0   = 10240;                      // WTp region base (elems)
    __shared__ unsigned short Sm[3 * BUFE];           // 72KB (reused in epilogue)

    const int tid  = threadIdx.x;
    const int wave = tid >> 6;
    const int lane = tid & 63;
    const int n_   = lane & 15;
    const int q    = lane >> 4;
    const int wm   = wave >> 2;
    const int wn   = wave & 3;

    const int bb = blockIdx.x;
    const int b  = bb & 7;
    const int rt = bb >> 3;
    const int row0 = b * 2048 + rt * 64;

    const unsigned short* Ag = adjb + (size_t)row0 * 2048;
    const unsigned short* Bg = HsTin + (size_t)b * (128 * 2048);

    const int lr  = lane >> 3;
    const int sch = (lane & 7) ^ lr;
    const unsigned short* Asg = Ag + (size_t)(wave * 8 + lr) * 2048 + sch * 8;
    const int dstA = wave * 512;
    const unsigned short* Bsg0 = Bg + (size_t)(wave * 16 + lr) * 2048 + sch * 8;
    const unsigned short* Bsg1 = Bsg0 + 8 * 2048;
    const int dstB = ABUFE + wave * 1024;

    const int swz = n_ & 7;
    int aoff[2][2], boff[2][2];
#pragma unroll
    for (int mi = 0; mi < 2; ++mi)
#pragma unroll
        for (int s = 0; s < 2; ++s)
            aoff[mi][s] = (wm * 32 + mi * 16 + n_) * 64 + (((s * 4 + q) ^ swz) * 8);
#pragma unroll
    for (int nj = 0; nj < 2; ++nj)
#pragma unroll
        for (int s = 0; s < 2; ++s)
            boff[nj][s] = ABUFE + (wn * 32 + nj * 16 + n_) * 64 + (((s * 4 + q) ^ swz) * 8);

    f32x4 acc[2][2];
#pragma unroll
    for (int i = 0; i < 2; ++i)
#pragma unroll
        for (int j = 0; j < 2; ++j) acc[i][j] = (f32x4){0.f, 0.f, 0.f, 0.f};

#pragma unroll
    for (int t = 0; t < 3; ++t) {
        const int kofs = t * 64;
        unsigned short* base = &Sm[t * BUFE];
        gl2lds16(Asg + kofs, base + dstA);
        gl2lds16(Bsg0 + kofs, base + dstB);
        gl2lds16(Bsg1 + kofs, base + dstB + 512);
    }

    int cur = 0;
#pragma unroll 1
    for (int t = 0; t < 32; ++t) {
        asm volatile("s_waitcnt vmcnt(6)" ::: "memory");
        __builtin_amdgcn_s_barrier();
        asm volatile("" ::: "memory");
        const unsigned short* sb = &Sm[cur * BUFE];
#pragma unroll
        for (int s = 0; s < 2; ++s) {
            bf16x8 a0 = *(const bf16x8*)(sb + aoff[0][s]);
            bf16x8 a1 = *(const bf16x8*)(sb + aoff[1][s]);
            bf16x8 b0 = *(const bf16x8*)(sb + boff[0][s]);
            bf16x8 b1 = *(const bf16x8*)(sb + boff[1][s]);
            acc[0][0] = __builtin_amdgcn_mfma_f32_16x16x32_bf16(a0, b0, acc[0][0], 0, 0, 0);
            acc[1][0] = __builtin_amdgcn_mfma_f32_16x16x32_bf16(a1, b0, acc[1][0], 0, 0, 0);
            acc[0][1] = __builtin_amdgcn_mfma_f32_16x16x32_bf16(a0, b1, acc[0][1], 0, 0, 0);
            acc[1][1] = __builtin_amdgcn_mfma_f32_16x16x32_bf16(a1, b1, acc[1][1], 0, 0, 0);
        }
        asm volatile("" ::: "memory");
        __builtin_amdgcn_s_barrier();
        asm volatile("" ::: "memory");
        {
            const int kofs = ((t + 3) & 31) * 64;
            unsigned short* base = &Sm[cur * BUFE];
            gl2lds16(Asg + kofs, base + dstA);
            gl2lds16(Bsg0 + kofs, base + dstB);
            gl2lds16(Bsg1 + kofs, base + dstB + 512);
        }
        cur = (cur == 2) ? 0 : cur + 1;
    }

    // ---- fused epilogue ---------------------------------------------------
    // drain wrapped stages (they target ring regions we now reuse) + barrier
    asm volatile("s_waitcnt vmcnt(0)" ::: "memory");
    __syncthreads();

    // (1) v = acc*dinv_i [+resid]; write Xout (bf16) and X-tile into LDS
    const int rb = row0 + wm * 32 + q * 4;
    float dsc[2][4];
#pragma unroll
    for (int mi = 0; mi < 2; ++mi)
#pragma unroll
        for (int r = 0; r < 4; ++r) dsc[mi][r] = dinv[rb + mi * 16 + r];
#pragma unroll
    for (int mi = 0; mi < 2; ++mi) {
#pragma unroll
        for (int nj = 0; nj < 2; ++nj) {
            const int f = wn * 32 + nj * 16 + n_;
#pragma unroll
            for (int r = 0; r < 4; ++r) {
                const size_t gr = (size_t)(rb + mi * 16 + r);
                float v = acc[mi][nj][r] * dsc[mi][r];
                if (MODE == 2) v += bf2f(resid[gr * 128 + f]);
                const unsigned short hv = f2bf(v);
                if (WRX) Xout[gr * 128 + f] = hv;
                Sm[(wm * 32 + mi * 16 + q * 4 + r) * LDX + f] = hv;  // X-tile
            }
        }
    }
    // (2) reg-stage WTn (32KB) into padded LDS region [XW0, XW0+128*136)
    {
        const int row = tid >> 2;                     // 0..127
        const int c0  = (tid & 3) * 32;
        const unsigned short* src = WTn + row * 128 + c0;
        unsigned short* dst = &Sm[XW0 + row * LDX + c0];
#pragma unroll
        for (int k = 0; k < 4; ++k)
            *(uint4*)(dst + k * 8) = *(const uint4*)(src + k * 8);
    }
    __syncthreads();

    // (3) mini-GEMM: H = leakyrelu(Xtile @ Wn + bn) * dinv_j -> HsTout
    // wave: j-half jh = wave>>2, f-quarter fq = wave&3; acc 2x2; gxw k-order.
    const int jh = wave >> 2;
    const int fq = wave & 3;
    f32x4 ah[2][2];
#pragma unroll
    for (int i = 0; i < 2; ++i)
#pragma unroll
        for (int j = 0; j < 2; ++j) ah[i][j] = (f32x4){0.f, 0.f, 0.f, 0.f};
#pragma unroll
    for (int s = 0; s < 4; ++s) {
        bf16x8 xa0 = *(const bf16x8*)(&Sm[(jh * 32 + n_) * LDX + s * 32 + q * 8]);
        bf16x8 xa1 = *(const bf16x8*)(&Sm[(jh * 32 + 16 + n_) * LDX + s * 32 + q * 8]);
        bf16x8 wb0 = *(const bf16x8*)(&Sm[XW0 + (fq * 32 + n_) * LDX + s * 32 + q * 8]);
        bf16x8 wb1 = *(const bf16x8*)(&Sm[XW0 + (fq * 32 + 16 + n_) * LDX + s * 32 + q * 8]);
        ah[0][0] = __builtin_amdgcn_mfma_f32_16x16x32_bf16(xa0, wb0, ah[0][0], 0, 0, 0);
        ah[1][0] = __builtin_amdgcn_mfma_f32_16x16x32_bf16(xa1, wb0, ah[1][0], 0, 0, 0);
        ah[0][1] = __builtin_amdgcn_mfma_f32_16x16x32_bf16(xa0, wb1, ah[0][1], 0, 0, 0);
        ah[1][1] = __builtin_amdgcn_mfma_f32_16x16x32_bf16(xa1, wb1, ah[1][1], 0, 0, 0);
    }
    // (4) gxw-identical epilogue: rows = j (q*4+r), cols = f (n_)
    const int jg0 = row0 + jh * 32 + q * 4;           // global j for dinv
    const int jb  = (row0 & 2047) + jh * 32 + q * 4;  // j within batch
    float dh[2][4];
#pragma unroll
    for (int mi = 0; mi < 2; ++mi)
#pragma unroll
        for (int r = 0; r < 4; ++r) dh[mi][r] = dinv[jg0 + mi * 16 + r];
    unsigned short* Hb = HsTout + (size_t)b * (128 * 2048);
#pragma unroll
    for (int mi = 0; mi < 2; ++mi) {
#pragma unroll
        for (int nj = 0; nj < 2; ++nj) {
            const int f = fq * 32 + nj * 16 + n_;
            const float bf = biasn[f];
            unsigned short pk[4];
#pragma unroll
            for (int r = 0; r < 4; ++r) {
                float v = ah[mi][nj][r] + bf;
                v = (v > 0.f) ? v : 0.01f * v;        // LeakyReLU(0.01)
                pk[r] = f2bf(v * dh[mi][r]);          // * dinv_j
            }
            uint2 uo;
            uo.x = (unsigned int)pk[0] | ((unsigned int)pk[1] << 16);
            uo.y = (unsigned int)pk[2] | ((unsigned int)pk[3] << 16);
            *(uint2*)(Hb + (size_t)f * 2048 + jb + mi * 16) = uo;
        }
    }
}

extern "C" void kernel_launch(void* const* d_in, const int* in_sizes, int n_in,
                              void* d_out, int out_size, void* d_ws, size_t ws_size,
                              hipStream_t stream) {
    const float* X   = (const float*)d_in[0];
    const float* adj = (const float*)d_in[1];
    const float* W1  = (const float*)d_in[2];
    const float* b1  = (const float*)d_in[3];
    const float* W2  = (const float*)d_in[4];
    const float* b2  = (const float*)d_in[5];
    const float* W3  = (const float*)d_in[6];
    const float* b3  = (const float*)d_in[7];

    // ws: adjb @0 (64 MiB) | dinv @64M | biasf @64M+64K | WT @64M+128K |
    //     HsTa @64M+256K (4M) | HsTb @68M+256K (4M) | Xa @72M+256K (4M)
    char* ws = (char*)d_ws;
    unsigned short* adjb  = (unsigned short*)ws;
    float*          dinv  = (float*)(ws + (64u << 20));
    float*          biasf = (float*)(ws + (64u << 20) + (64u << 10));
    unsigned short* WT    = (unsigned short*)(ws + (64u << 20) + (128u << 10));
    unsigned short* HsTa  = (unsigned short*)(ws + (64u << 20) + (256u << 10));
    unsigned short* HsTb  = (unsigned short*)(ws + (68u << 20) + (256u << 10));
    unsigned short* Xa    = (unsigned short*)(ws + (72u << 20) + (256u << 10));

    k_pre<<<16578, 256, 0, stream>>>(adj, W1, W2, W3, b1, b2, b3, dinv, adjb, WT, biasf);

    // layer 1 small GEMM
    k_gxw<1><<<512, 256, 0, stream>>>(X, WT, biasf, dinv, HsTa);
    // layer 1 big GEMM + fused layer-2 small GEMM  (writes Xa + HsTb)
    k_gahx<1, 1><<<256, 512, 0, stream>>>(adjb, HsTa, dinv, nullptr, Xa,
                                          WT + 16384, biasf + 128, HsTb);
    // layer 2 big GEMM (+resid Xa) + fused layer-3 small GEMM (writes HsTa)
    k_gahx<2, 0><<<256, 512, 0, stream>>>(adjb, HsTb, dinv, Xa, nullptr,
                                          WT + 32768, biasf + 256, HsTa);
    // layer 3 big GEMM -> fp32 out
    k_gah<1, 1><<<256, 512, 0, stream>>>(adjb, HsTa, dinv, nullptr, (float*)d_out);
}